// Round 7
// baseline (55.216 us; speedup 1.0000x reference)
//
#include <hip/hip_runtime.h>
#include <hip/hip_bf16.h>

#define BTOT 128     // B*T
#define NN   512
#define FIN  128
#define FOUT 64

typedef __attribute__((ext_vector_type(8))) short bf16x8;
typedef __attribute__((ext_vector_type(4))) float f32x4;

static __device__ inline ushort f2bf(float f) {
    __hip_bfloat16 h = __float2bfloat16(f);
    return *(ushort*)&h;
}
static __device__ inline float bf2f(ushort u) {
    uint v = (uint)u << 16;
    return __uint_as_float(v);
}

// ---------- P: prep W split (blocks 256..287) + cd pack (blocks 0..255) ----------
// cd word: hi16 = bf16(w*log2e) if conn else 0; lo16 = bf16(-inf) if (!conn && w>0) else 0.
// p = exp2(fma(c, leaky(s), d)) reproduces all ref corner cases (incl. w==0).
__global__ void k_prep(const float* __restrict__ W, const int* __restrict__ adj,
                       const float* __restrict__ we, ushort* __restrict__ Whi,
                       ushort* __restrict__ Wlo, uint* __restrict__ cd) {
    int b = blockIdx.x;
    if (b >= 256) {       // W split: 8192 elems over 32 blocks
        int i = (b - 256) * 256 + threadIdx.x;
        float w = W[i];
        ushort hi = f2bf(w);
        Whi[i] = hi;
        Wlo[i] = f2bf(w - bf2f(hi));
        return;
    }
    int i = (b * 256 + threadIdx.x) * 4;     // 262144 words
    int4   a4 = *(const int4*)&adj[i];
    float4 w4 = *(const float4*)&we[i];
    uint o[4];
#pragma unroll
    for (int e = 0; e < 4; ++e) {
        bool  cn = ((const int*)&a4)[e] > 0;
        float w  = ((const float*)&w4)[e];
        ushort cb = cn ? f2bf(w * 1.44269504f) : (ushort)0;
        ushort db = (!cn && w > 0.f) ? (ushort)0xFF80 : (ushort)0;   // -inf bf16
        o[e] = ((uint)cb << 16) | db;
    }
    *(uint4*)&cd[i] = *(uint4*)&o[0];
}

// ---------- A: h = x @ W^T via bf16x3 MFMA; emit ht bf16 [bt][o][n], src, dst ----
__global__ void k_feat(const float* __restrict__ x, const ushort* __restrict__ Whi,
                       const ushort* __restrict__ Wlo, const float* __restrict__ a,
                       ushort* __restrict__ ht, float* __restrict__ srcv,
                       float* __restrict__ dstv) {
    const int t    = threadIdx.x;
    const int bt   = blockIdx.y;
    const int wv   = t >> 6, lane = t & 63;
    const int r    = lane & 15;          // A-row / B-col within 16; C/D col
    const int kc   = lane >> 4;          // k-chunk; C/D row group
    const int n0   = blockIdx.x * 64 + wv * 16;

    const float* xrow = x + ((long)bt * NN + n0 + r) * FIN;

    f32x4 acc[4] = {{0,0,0,0},{0,0,0,0},{0,0,0,0},{0,0,0,0}};

#pragma unroll
    for (int ks = 0; ks < 4; ++ks) {
        float4 xa = *(const float4*)&xrow[ks * 32 + kc * 8];
        float4 xb = *(const float4*)&xrow[ks * 32 + kc * 8 + 4];
        float xv[8] = {xa.x, xa.y, xa.z, xa.w, xb.x, xb.y, xb.z, xb.w};
        bf16x8 Ahi, Alo;
#pragma unroll
        for (int e = 0; e < 8; ++e) {
            uint b = __float_as_uint(xv[e]);
            float hf = __uint_as_float(b & 0xFFFF0000u);
            Ahi[e] = (short)(b >> 16);
            float rr = xv[e] - hf;                       // exact
            Alo[e] = (short)(__float_as_uint(rr) >> 16); // trunc
        }
#pragma unroll
        for (int g = 0; g < 4; ++g) {
            const int wo = (g * 16 + r) * FIN + ks * 32 + kc * 8;
            bf16x8 Bhi = *(const bf16x8*)&Whi[wo];
            bf16x8 Blo = *(const bf16x8*)&Wlo[wo];
            acc[g] = __builtin_amdgcn_mfma_f32_16x16x32_bf16(Ahi, Bhi, acc[g], 0, 0, 0);
            acc[g] = __builtin_amdgcn_mfma_f32_16x16x32_bf16(Alo, Bhi, acc[g], 0, 0, 0);
            acc[g] = __builtin_amdgcn_mfma_f32_16x16x32_bf16(Ahi, Blo, acc[g], 0, 0, 0);
        }
    }

    float a1g[4], a2g[4];
#pragma unroll
    for (int g = 0; g < 4; ++g) {
        a1g[g] = a[g * 16 + r];
        a2g[g] = a[FOUT + g * 16 + r];
    }
    f32x4 s1v = {0,0,0,0}, s2v = {0,0,0,0};
#pragma unroll
    for (int g = 0; g < 4; ++g)
#pragma unroll
        for (int reg = 0; reg < 4; ++reg) {
            s1v[reg] += acc[g][reg] * a1g[g];
            s2v[reg] += acc[g][reg] * a2g[g];
        }
#pragma unroll
    for (int off = 8; off; off >>= 1)
#pragma unroll
        for (int reg = 0; reg < 4; ++reg) {
            s1v[reg] += __shfl_down(s1v[reg], off, 16);
            s2v[reg] += __shfl_down(s2v[reg], off, 16);
        }
    if (r == 0) {
        float4 o1 = make_float4(s1v[0], s1v[1], s1v[2], s1v[3]);
        float4 o2 = make_float4(s2v[0], s2v[1], s2v[2], s2v[3]);
        *(float4*)&srcv[bt * NN + n0 + kc * 4] = o1;
        *(float4*)&dstv[bt * NN + n0 + kc * 4] = o2;
    }

#pragma unroll
    for (int g = 0; g < 4; ++g) {
        uint2 pk;
        pk.x = (uint)f2bf(acc[g][0]) | ((uint)f2bf(acc[g][1]) << 16);
        pk.y = (uint)f2bf(acc[g][2]) | ((uint)f2bf(acc[g][3]) << 16);
        *(uint2*)&ht[(long)bt * (FOUT * NN) + (g * 16 + r) * NN + n0 + kc * 4] = pk;
    }
}

// p-values -> A-fragment, all in registers (no LDS transit)
static __device__ inline bf16x8 make_afrag(uint4 ca, uint4 cb, float4 d0, float4 d1,
                                           float si) {
    float dv[8] = {d0.x, d0.y, d0.z, d0.w, d1.x, d1.y, d1.z, d1.w};
    uint  cw[8] = {ca.x, ca.y, ca.z, ca.w, cb.x, cb.y, cb.z, cb.w};
    bf16x8 A;
#pragma unroll
    for (int e = 0; e < 8; ++e) {
        float cf = __uint_as_float(cw[e] & 0xFFFF0000u);
        float df = __uint_as_float(cw[e] << 16);
        float s  = si + dv[e];
        float lr = fmaxf(s, 0.01f * s);
        A[e] = (short)f2bf(__builtin_amdgcn_exp2f(fmaf(cf, lr, df)));
    }
    return A;
}

// ---------- B: fused att + bf16 MFMA PV, barrier-free main loop ----------
// bid = it*128 + bt => XCD = bt%8; per XCD: 1MB ht + cd slices, L2-resident.
// Each lane computes exactly the 16 p-values its own MFMA A-frags need
// (row = i0+16wv+(lane&15), k = s2*32+(lane>>4)*8+e) -> no ps LDS, no per-jt
// barriers. h^T staged per 256-k half into XOR-swizzled LDS (4 barriers total).
__global__ __launch_bounds__(256, 4)
void k_attn(const ushort* __restrict__ ht, const float* __restrict__ srcv,
            const float* __restrict__ dstv, const uint* __restrict__ cd,
            float* __restrict__ out) {
    __shared__ ushort hs[64 * 256];   // [o][k-half], c8 ^= (o&7) swizzle
    __shared__ float dst_s[NN];

    const int t    = threadIdx.x;
    const int bid  = blockIdx.x;
    const int bt   = bid & 127;
    const int i0   = (bid >> 7) << 6;
    const int lane = t & 63;
    const int wv   = t >> 6;
    const int r16  = lane & 15;
    const int kq   = lane >> 4;          // 0..3
    const int koff = kq * 8;
    const int xr   = r16 & 7;            // B-read swizzle term (same for all 4 col-blocks)

    const int ri = i0 + wv * 16 + r16;   // my A-row
    const float si = srcv[bt * NN + ri];
    const uint* cdr   = cd + ri * NN;
    const ushort* htb = ht + (long)bt * (FOUT * NN);

    for (int q = t; q < NN; q += 256) dst_s[q] = dstv[bt * NN + q];

    f32x4 acc0 = {0,0,0,0}, acc1 = {0,0,0,0}, acc2 = {0,0,0,0},
          acc3 = {0,0,0,0}, accd = {0,0,0,0};
    bf16x8 ones;
#pragma unroll
    for (int j = 0; j < 8; ++j) ones[j] = (short)0x3F80;   // bf16 1.0

    for (int half = 0; half < 2; ++half) {
        __syncthreads();   // prev-half reads done; dst_s writes visible (half 0)
        // stage 32KB half-tile: [o][c8] -> hs[o][c8 ^ (o&7)]
#pragma unroll
        for (int q = 0; q < 8; ++q) {
            int idx = q * 256 + t;            // 0..2047
            int o = idx >> 5, c8 = idx & 31;
            float4 v = *(const float4*)&htb[(o << 9) + (half << 8) + (c8 << 3)];
            *(float4*)&hs[(o << 8) + ((c8 ^ (o & 7)) << 3)] = v;
        }
        __syncthreads();

        const int jg = half * 256;
        uint4 cA0 = *(const uint4*)&cdr[jg + koff];
        uint4 cA1 = *(const uint4*)&cdr[jg + koff + 4];
        uint4 cB0 = *(const uint4*)&cdr[jg + 32 + koff];
        uint4 cB1 = *(const uint4*)&cdr[jg + 32 + koff + 4];

#pragma unroll
        for (int jtl = 0; jtl < 4; ++jtl) {
            const int jgc = jg + jtl * 64;
            uint4 nA0 = {0,0,0,0}, nA1 = {0,0,0,0}, nB0 = {0,0,0,0}, nB1 = {0,0,0,0};
            if (jtl < 3) {                      // prefetch next jt's cd
                nA0 = *(const uint4*)&cdr[jgc + 64 + koff];
                nA1 = *(const uint4*)&cdr[jgc + 64 + koff + 4];
                nB0 = *(const uint4*)&cdr[jgc + 96 + koff];
                nB1 = *(const uint4*)&cdr[jgc + 96 + koff + 4];
            }
            float4 d00 = *(float4*)&dst_s[jgc + koff];
            float4 d01 = *(float4*)&dst_s[jgc + koff + 4];
            float4 d10 = *(float4*)&dst_s[jgc + 32 + koff];
            float4 d11 = *(float4*)&dst_s[jgc + 32 + koff + 4];

            bf16x8 A0 = make_afrag(cA0, cA1, d00, d01, si);   // s2 = 0
            bf16x8 A1 = make_afrag(cB0, cB1, d10, d11, si);   // s2 = 1

#pragma unroll
            for (int s2 = 0; s2 < 2; ++s2) {
                bf16x8 A = s2 ? A1 : A0;
                const int c8v = jtl * 8 + s2 * 4 + kq;
                const int cs  = (c8v ^ xr) << 3;
                bf16x8 b0 = *(bf16x8*)&hs[(( 0 + r16) << 8) + cs];
                bf16x8 b1 = *(bf16x8*)&hs[((16 + r16) << 8) + cs];
                bf16x8 b2 = *(bf16x8*)&hs[((32 + r16) << 8) + cs];
                bf16x8 b3 = *(bf16x8*)&hs[((48 + r16) << 8) + cs];
                acc0 = __builtin_amdgcn_mfma_f32_16x16x32_bf16(A, b0, acc0, 0, 0, 0);
                acc1 = __builtin_amdgcn_mfma_f32_16x16x32_bf16(A, b1, acc1, 0, 0, 0);
                acc2 = __builtin_amdgcn_mfma_f32_16x16x32_bf16(A, b2, acc2, 0, 0, 0);
                acc3 = __builtin_amdgcn_mfma_f32_16x16x32_bf16(A, b3, acc3, 0, 0, 0);
                accd = __builtin_amdgcn_mfma_f32_16x16x32_bf16(A, ones, accd, 0, 0, 0);
            }
            cA0 = nA0; cA1 = nA1; cB0 = nB0; cB1 = nB1;
        }
    }

    // epilogue: C/D layout col=lane&15, row=(lane>>4)*4+reg; den in accd same slots
    const int orow = wv * 16 + (lane >> 4) * 4;
    const int ocol = lane & 15;
    float* ob = out + ((long)bt * NN + i0) * FOUT;
#pragma unroll
    for (int reg = 0; reg < 4; ++reg) {
        float inv = 1.0f / accd[reg];
        ob[(orow + reg) * FOUT +  0 + ocol] = acc0[reg] * inv;
        ob[(orow + reg) * FOUT + 16 + ocol] = acc1[reg] * inv;
        ob[(orow + reg) * FOUT + 32 + ocol] = acc2[reg] * inv;
        ob[(orow + reg) * FOUT + 48 + ocol] = acc3[reg] * inv;
    }
}

extern "C" void kernel_launch(void* const* d_in, const int* in_sizes, int n_in,
                              void* d_out, int out_size, void* d_ws, size_t ws_size,
                              hipStream_t stream) {
    const float* x      = (const float*)d_in[0];
    const float* W      = (const float*)d_in[1];
    const float* a      = (const float*)d_in[2];
    const int*   adj    = (const int*)d_in[3];
    const float* adj_we = (const float*)d_in[4];
    float* out = (float*)d_out;

    ushort* Whi  = (ushort*)d_ws;                      // 8192 bf16
    ushort* Wlo  = Whi + FOUT * FIN;                   // 8192 bf16
    ushort* ht   = Wlo + FOUT * FIN;                   // 128*64*512 bf16
    float*  srcv = (float*)(ht + BTOT * FOUT * NN);    // 65536 fp32
    float*  dstv = srcv + BTOT * NN;                   // 65536 fp32
    uint*   cdw  = (uint*)(dstv + BTOT * NN);          // 262144 words

    hipLaunchKernelGGL(k_prep, dim3(288), dim3(256), 0, stream,
                       W, adj, adj_we, Whi, Wlo, cdw);
    hipLaunchKernelGGL(k_feat, dim3(8, 128), dim3(256), 0, stream,
                       x, Whi, Wlo, a, ht, srcv, dstv);
    hipLaunchKernelGGL(k_attn, dim3(1024), dim3(256), 0, stream,
                       ht, srcv, dstv, cdw, out);
}

// Round 8
// 48.224 us; speedup vs baseline: 1.1450x; 1.1450x over previous
//
#include <hip/hip_runtime.h>
#include <hip/hip_bf16.h>

#define BTOT 128     // B*T
#define NN   512
#define FIN  128
#define FOUT 64

typedef __attribute__((ext_vector_type(8))) short bf16x8;
typedef __attribute__((ext_vector_type(4))) float f32x4;

static __device__ inline ushort f2bf(float f) {
    __hip_bfloat16 h = __float2bfloat16(f);
    return *(ushort*)&h;
}
static __device__ inline float bf2f(ushort u) {
    uint v = (uint)u << 16;
    return __uint_as_float(v);
}

// ---------- P: prep W split (blocks 256..287) + cd pack (blocks 0..255) ----------
// cd ushort: bits15..1 = w*log2e rounded-NE to 7-bit mantissa; bit0 = "p nonzero"
// (= conn || w==0). Decode: c = uint(u<<16)&0xFFFE0000 (fp32), m = u&1.
// p = m ? exp2(c * leaky(s)) : 0 reproduces every ref corner case:
//   conn:            p = exp2(w*log2e*lr) = exp(w*lr)        (c err <= 2^-8 rel)
//   conn, w==0:      c==0, m=1 -> p=1                        (ref exp(0)=1)
//   disc, w>0:       m=0 -> p=0                              (ref exp(-9e15*w)=0)
//   disc, w==0:      c==0, m=1 -> p=1                        (ref exp(-0)=1)
__global__ void k_prep(const float* __restrict__ W, const int* __restrict__ adj,
                       const float* __restrict__ we, ushort* __restrict__ Whi,
                       ushort* __restrict__ Wlo, ushort* __restrict__ cds) {
    int b = blockIdx.x;
    if (b >= 256) {       // W split: 8192 elems over 32 blocks
        int i = (b - 256) * 256 + threadIdx.x;
        float w = W[i];
        ushort hi = f2bf(w);
        Whi[i] = hi;
        Wlo[i] = f2bf(w - bf2f(hi));
        return;
    }
    int i = (b * 256 + threadIdx.x) * 4;     // 262144 edges
    int4   a4 = *(const int4*)&adj[i];
    float4 w4 = *(const float4*)&we[i];
    ushort o[4];
#pragma unroll
    for (int e = 0; e < 4; ++e) {
        bool  cn = ((const int*)&a4)[e] > 0;
        float w  = ((const float*)&w4)[e];
        if (cn) {
            uint ub = __float_as_uint(w * 1.44269504f);
            uint t  = ub + 0xFFFFu + ((ub >> 17) & 1u);       // RNE @ 7-bit mantissa
            o[e] = (ushort)(((t >> 17) << 1) | 1u);
        } else {
            o[e] = (w > 0.f) ? (ushort)0 : (ushort)1;         // p=0 | p=1
        }
    }
    *(uint2*)&cds[i] = *(uint2*)&o[0];
}

// ---------- A: h = x @ W^T via bf16x3 MFMA; emit ht bf16 [bt][o][n], src, dst ----
// 1D grid 1024, bid = ntile*128 + bt  =>  XCD = bt%8 — ht lands in the SAME
// XCD L2 that k_attn (also bt-major) reads it from. x loads non-temporal.
__global__ void k_feat(const float* __restrict__ x, const ushort* __restrict__ Whi,
                       const ushort* __restrict__ Wlo, const float* __restrict__ a,
                       ushort* __restrict__ ht, float* __restrict__ srcv,
                       float* __restrict__ dstv) {
    const int t    = threadIdx.x;
    const int bid  = blockIdx.x;
    const int bt   = bid & 127;
    const int nt   = bid >> 7;
    const int wv   = t >> 6, lane = t & 63;
    const int r    = lane & 15;          // A-row / B-col within 16; C/D col
    const int kc   = lane >> 4;          // k-chunk; C/D row group
    const int n0   = nt * 64 + wv * 16;

    const float* xrow = x + ((long)bt * NN + n0 + r) * FIN;

    f32x4 acc[4] = {{0,0,0,0},{0,0,0,0},{0,0,0,0},{0,0,0,0}};

#pragma unroll
    for (int ks = 0; ks < 4; ++ks) {
        f32x4 xa = __builtin_nontemporal_load((const f32x4*)&xrow[ks * 32 + kc * 8]);
        f32x4 xb = __builtin_nontemporal_load((const f32x4*)&xrow[ks * 32 + kc * 8 + 4]);
        float xv[8] = {xa[0], xa[1], xa[2], xa[3], xb[0], xb[1], xb[2], xb[3]};
        bf16x8 Ahi, Alo;
#pragma unroll
        for (int e = 0; e < 8; ++e) {
            uint b = __float_as_uint(xv[e]);
            float hf = __uint_as_float(b & 0xFFFF0000u);
            Ahi[e] = (short)(b >> 16);
            float rr = xv[e] - hf;                       // exact (Sterbenz)
            Alo[e] = (short)(__float_as_uint(rr) >> 16); // trunc
        }
#pragma unroll
        for (int g = 0; g < 4; ++g) {
            const int wo = (g * 16 + r) * FIN + ks * 32 + kc * 8;
            bf16x8 Bhi = *(const bf16x8*)&Whi[wo];
            bf16x8 Blo = *(const bf16x8*)&Wlo[wo];
            acc[g] = __builtin_amdgcn_mfma_f32_16x16x32_bf16(Ahi, Bhi, acc[g], 0, 0, 0);
            acc[g] = __builtin_amdgcn_mfma_f32_16x16x32_bf16(Alo, Bhi, acc[g], 0, 0, 0);
            acc[g] = __builtin_amdgcn_mfma_f32_16x16x32_bf16(Ahi, Blo, acc[g], 0, 0, 0);
        }
    }

    float a1g[4], a2g[4];
#pragma unroll
    for (int g = 0; g < 4; ++g) {
        a1g[g] = a[g * 16 + r];
        a2g[g] = a[FOUT + g * 16 + r];
    }
    f32x4 s1v = {0,0,0,0}, s2v = {0,0,0,0};
#pragma unroll
    for (int g = 0; g < 4; ++g)
#pragma unroll
        for (int reg = 0; reg < 4; ++reg) {
            s1v[reg] += acc[g][reg] * a1g[g];
            s2v[reg] += acc[g][reg] * a2g[g];
        }
#pragma unroll
    for (int off = 8; off; off >>= 1)
#pragma unroll
        for (int reg = 0; reg < 4; ++reg) {
            s1v[reg] += __shfl_down(s1v[reg], off, 16);
            s2v[reg] += __shfl_down(s2v[reg], off, 16);
        }
    if (r == 0) {
        float4 o1 = make_float4(s1v[0], s1v[1], s1v[2], s1v[3]);
        float4 o2 = make_float4(s2v[0], s2v[1], s2v[2], s2v[3]);
        *(float4*)&srcv[bt * NN + n0 + kc * 4] = o1;
        *(float4*)&dstv[bt * NN + n0 + kc * 4] = o2;
    }

#pragma unroll
    for (int g = 0; g < 4; ++g) {
        uint2 pk;
        pk.x = (uint)f2bf(acc[g][0]) | ((uint)f2bf(acc[g][1]) << 16);
        pk.y = (uint)f2bf(acc[g][2]) | ((uint)f2bf(acc[g][3]) << 16);
        *(uint2*)&ht[(long)bt * (FOUT * NN) + (g * 16 + r) * NN + n0 + kc * 4] = pk;
    }
}

// 8 packed cd ushorts + dst -> A-fragment (registers only). p packed by trunc
// (softmax is scale-invariant; truncation bias is common-mode with accd).
static __device__ inline bf16x8 make_afrag(uint4 c, float4 d0, float4 d1, float si) {
    float dv[8] = {d0.x, d0.y, d0.z, d0.w, d1.x, d1.y, d1.z, d1.w};
    uint  cw[4] = {c.x, c.y, c.z, c.w};
    bf16x8 A;
#pragma unroll
    for (int q = 0; q < 4; ++q) {
        uint u = cw[q];
        float c0 = __uint_as_float((u << 16) & 0xFFFE0000u);
        float c1 = __uint_as_float(u & 0xFFFE0000u);
        float s0 = si + dv[2 * q],     lr0 = fmaxf(s0, 0.01f * s0);
        float s1 = si + dv[2 * q + 1], lr1 = fmaxf(s1, 0.01f * s1);
        float p0 = __builtin_amdgcn_exp2f(c0 * lr0);
        float p1 = __builtin_amdgcn_exp2f(c1 * lr1);
        p0 = (u & 1u)       ? p0 : 0.f;
        p1 = (u & 0x10000u) ? p1 : 0.f;
        A[2 * q]     = (short)(__float_as_uint(p0) >> 16);
        A[2 * q + 1] = (short)(__float_as_uint(p1) >> 16);
    }
    return A;
}

// ---------- B: fused att + bf16 MFMA PV, barrier-free main loop ----------
// bid = it*128 + bt => XCD = bt%8; per XCD: 1MB ht + 0.5MB cd, L2-resident
// (out writes are non-temporal so they no longer evict the L2 working set).
__global__ __launch_bounds__(256, 4)
void k_attn(const ushort* __restrict__ ht, const float* __restrict__ srcv,
            const float* __restrict__ dstv, const ushort* __restrict__ cds,
            float* __restrict__ out) {
    __shared__ ushort hs[64 * 256];   // [o][k-half], c8 ^= (o&7) swizzle
    __shared__ float dst_s[NN];

    const int t    = threadIdx.x;
    const int bid  = blockIdx.x;
    const int bt   = bid & 127;
    const int i0   = (bid >> 7) << 6;
    const int lane = t & 63;
    const int wv   = t >> 6;
    const int r16  = lane & 15;
    const int kq   = lane >> 4;          // 0..3
    const int koff = kq * 8;
    const int xr   = r16 & 7;            // B-read swizzle term

    const int ri = i0 + wv * 16 + r16;   // my A-row
    const float si = srcv[bt * NN + ri];
    const ushort* cdr = cds + ri * NN;
    const ushort* htb = ht + (long)bt * (FOUT * NN);

    for (int q = t; q < NN; q += 256) dst_s[q] = dstv[bt * NN + q];

    f32x4 acc0 = {0,0,0,0}, acc1 = {0,0,0,0}, acc2 = {0,0,0,0},
          acc3 = {0,0,0,0}, accd = {0,0,0,0};
    bf16x8 ones;
#pragma unroll
    for (int j = 0; j < 8; ++j) ones[j] = (short)0x3F80;   // bf16 1.0

    for (int half = 0; half < 2; ++half) {
        __syncthreads();   // prev-half reads done; dst_s writes visible (half 0)
        // stage 32KB half-tile: [o][c8] -> hs[o][c8 ^ (o&7)]
#pragma unroll
        for (int q = 0; q < 8; ++q) {
            int idx = q * 256 + t;            // 0..2047
            int o = idx >> 5, c8 = idx & 31;
            float4 v = *(const float4*)&htb[(o << 9) + (half << 8) + (c8 << 3)];
            *(float4*)&hs[(o << 8) + ((c8 ^ (o & 7)) << 3)] = v;
        }
        __syncthreads();

        const int jg = half * 256;
        uint4 cA = *(const uint4*)&cdr[jg + koff];        // 8 cd for s2=0
        uint4 cB = *(const uint4*)&cdr[jg + 32 + koff];   // 8 cd for s2=1

#pragma unroll
        for (int jtl = 0; jtl < 4; ++jtl) {
            const int jgc = jg + jtl * 64;
            uint4 nA = {0,0,0,0}, nB = {0,0,0,0};
            if (jtl < 3) {                      // prefetch next jt's cd
                nA = *(const uint4*)&cdr[jgc + 64 + koff];
                nB = *(const uint4*)&cdr[jgc + 96 + koff];
            }
            float4 d00 = *(float4*)&dst_s[jgc + koff];
            float4 d01 = *(float4*)&dst_s[jgc + koff + 4];
            float4 d10 = *(float4*)&dst_s[jgc + 32 + koff];
            float4 d11 = *(float4*)&dst_s[jgc + 32 + koff + 4];

            bf16x8 A0 = make_afrag(cA, d00, d01, si);   // s2 = 0
            bf16x8 A1 = make_afrag(cB, d10, d11, si);   // s2 = 1

#pragma unroll
            for (int s2 = 0; s2 < 2; ++s2) {
                bf16x8 A = s2 ? A1 : A0;
                const int c8v = jtl * 8 + s2 * 4 + kq;
                const int cs  = (c8v ^ xr) << 3;
                bf16x8 b0 = *(bf16x8*)&hs[(( 0 + r16) << 8) + cs];
                bf16x8 b1 = *(bf16x8*)&hs[((16 + r16) << 8) + cs];
                bf16x8 b2 = *(bf16x8*)&hs[((32 + r16) << 8) + cs];
                bf16x8 b3 = *(bf16x8*)&hs[((48 + r16) << 8) + cs];
                acc0 = __builtin_amdgcn_mfma_f32_16x16x32_bf16(A, b0, acc0, 0, 0, 0);
                acc1 = __builtin_amdgcn_mfma_f32_16x16x32_bf16(A, b1, acc1, 0, 0, 0);
                acc2 = __builtin_amdgcn_mfma_f32_16x16x32_bf16(A, b2, acc2, 0, 0, 0);
                acc3 = __builtin_amdgcn_mfma_f32_16x16x32_bf16(A, b3, acc3, 0, 0, 0);
                accd = __builtin_amdgcn_mfma_f32_16x16x32_bf16(A, ones, accd, 0, 0, 0);
            }
            cA = nA; cB = nB;
        }
    }

    // epilogue: C/D layout col=lane&15, row=(lane>>4)*4+reg; den in accd same slots
    const int orow = wv * 16 + (lane >> 4) * 4;
    const int ocol = lane & 15;
    float* ob = out + ((long)bt * NN + i0) * FOUT;
#pragma unroll
    for (int reg = 0; reg < 4; ++reg) {
        float inv = 1.0f / accd[reg];
        __builtin_nontemporal_store(acc0[reg] * inv, &ob[(orow + reg) * FOUT +  0 + ocol]);
        __builtin_nontemporal_store(acc1[reg] * inv, &ob[(orow + reg) * FOUT + 16 + ocol]);
        __builtin_nontemporal_store(acc2[reg] * inv, &ob[(orow + reg) * FOUT + 32 + ocol]);
        __builtin_nontemporal_store(acc3[reg] * inv, &ob[(orow + reg) * FOUT + 48 + ocol]);
    }
}

extern "C" void kernel_launch(void* const* d_in, const int* in_sizes, int n_in,
                              void* d_out, int out_size, void* d_ws, size_t ws_size,
                              hipStream_t stream) {
    const float* x      = (const float*)d_in[0];
    const float* W      = (const float*)d_in[1];
    const float* a      = (const float*)d_in[2];
    const int*   adj    = (const int*)d_in[3];
    const float* adj_we = (const float*)d_in[4];
    float* out = (float*)d_out;

    ushort* Whi  = (ushort*)d_ws;                      // 8192 bf16
    ushort* Wlo  = Whi + FOUT * FIN;                   // 8192 bf16
    ushort* ht   = Wlo + FOUT * FIN;                   // 128*64*512 bf16
    float*  srcv = (float*)(ht + BTOT * FOUT * NN);    // 65536 fp32
    float*  dstv = srcv + BTOT * NN;                   // 65536 fp32
    ushort* cdsw = (ushort*)(dstv + BTOT * NN);        // 262144 ushorts

    hipLaunchKernelGGL(k_prep, dim3(288), dim3(256), 0, stream,
                       W, adj, adj_we, Whi, Wlo, cdsw);
    hipLaunchKernelGGL(k_feat, dim3(1024), dim3(256), 0, stream,
                       x, Whi, Wlo, a, ht, srcv, dstv);
    hipLaunchKernelGGL(k_attn, dim3(1024), dim3(256), 0, stream,
                       ht, srcv, dstv, cdsw, out);
}